// Round 6
// baseline (114.399 us; speedup 1.0000x reference)
//
#include <hip/hip_runtime.h>
#include <hip/hip_bf16.h>

typedef __bf16 bf16x8 __attribute__((ext_vector_type(8)));
typedef float  f32x4  __attribute__((ext_vector_type(4)));

#define MFMA16(a,b,c) __builtin_amdgcn_mfma_f32_16x16x32_bf16((a),(b),(c),0,0,0)

__device__ __forceinline__ unsigned short f2bf(float f){
  unsigned int u = __float_as_uint(f);
  u += 0x7fffu + ((u >> 16) & 1u);
  return (unsigned short)(u >> 16);
}

// pack 2 f32 -> 2 bf16 in one instr (RTE)
__device__ __forceinline__ unsigned int cvtpk(float lo, float hi){
  unsigned int r;
  asm("v_cvt_pk_bf16_f32 %0, %1, %2" : "=v"(r) : "v"(lo), "v"(hi));
  return r;
}

// LDS-visibility sync WITHOUT vmcnt(0) drain (keeps global loads in flight)
__device__ __forceinline__ void block_sync(){
  asm volatile("s_waitcnt lgkmcnt(0)" ::: "memory");
  __builtin_amdgcn_s_barrier();
}

constexpr float SCALE_LOG2E = 0.125f * 1.4426950408889634f; // 1/sqrt(64) * log2(e)

// ---------------- merged prep kernel ----------------
// blocks 0..31: qs + AqT fragments ; 32..287: Cmat+cvec ; 288..543: starts scan
__global__ void k_prep(const float* __restrict__ queries, const float* __restrict__ ipw,
                       const float* __restrict__ ipb, const float* __restrict__ opw,
                       const float* __restrict__ opb, const int* __restrict__ batch,
                       int total, int* __restrict__ starts,
                       unsigned short* __restrict__ AqF,
                       unsigned short* __restrict__ Cmat, float* __restrict__ cvec)
{
  __shared__ __align__(16) float sh[256];
  __shared__ __align__(16) float sh2[256];
  const int t = threadIdx.x, bid = blockIdx.x;

  if (bid < 32){
    const int q = bid;
    sh[t] = queries[q*256 + t];
    __syncthreads();
    const float* wr = ipw + (size_t)t*256;
    float acc = 0.f;
    #pragma unroll 8
    for (int j = 0; j < 256; j += 4){
      float4 wv = *reinterpret_cast<const float4*>(wr + j);
      float4 qv = *reinterpret_cast<const float4*>(&sh[j]);
      acc += wv.x*qv.x + wv.y*qv.y + wv.z*qv.z + wv.w*qv.w;
    }
    sh2[t] = acc + ipb[t];
    __syncthreads();
    #pragma unroll
    for (int h = 0; h < 4; h++){
      const float* wk = ipw + (size_t)(256 + h*64)*256 + t;
      float a2 = 0.f;
      #pragma unroll 8
      for (int d = 0; d < 64; d++) a2 += sh2[h*64 + d] * wk[(size_t)d*256];
      // B-frag layout: AqF[rg=h*2+qh][kb=f>>5][lane=((f>>3)&3)*16 + (q&15)][j=f&7]
      const int dst = ((h*2 + (q>>4))*8 + (t>>5))*512 + (((t>>3)&3)*16 + (q&15))*8 + (t&7);
      AqF[dst] = f2bf(a2 * SCALE_LOG2E);
    }
  } else if (bid < 288){
    const int g = bid - 32;
    sh[t] = opw[(size_t)g*256 + t];
    __syncthreads();
    #pragma unroll
    for (int h = 0; h < 4; h++){
      const float* wv = ipw + (size_t)(512 + h*64)*256 + t;
      float acc = 0.f;
      #pragma unroll 8
      for (int d = 0; d < 64; d++) acc += wv[(size_t)d*256] * sh[h*64 + d];
      Cmat[(size_t)g*1024 + h*256 + t] = f2bf(acc);
    }
    sh2[t] = ipb[512 + t] * sh[t];
    __syncthreads();
    for (int off = 128; off > 0; off >>= 1){
      if (t < off) sh2[t] += sh2[t + off];
      __syncthreads();
    }
    if (t == 0) cvec[g] = sh2[0] + opb[g];
  } else {
    const int sb = bid - 288;
    const int i0 = sb*1024 + t*4;
    if (i0 + 3 < total){
      if (i0 == 0) starts[0] = 0;
      const int4 b4 = *reinterpret_cast<const int4*>(batch + i0);
      if (b4.y != b4.x) starts[b4.y] = i0 + 1;
      if (b4.z != b4.y) starts[b4.z] = i0 + 2;
      if (b4.w != b4.z) starts[b4.w] = i0 + 3;
      if (i0 + 4 < total){
        const int nxt = batch[i0 + 4];
        if (nxt != b4.w) starts[nxt] = i0 + 4;
      } else {
        starts[128] = total;
      }
    }
  }
}

// ---------------- fused attention over raw x (no-max softmax) ----------------
// grid 256 = graph*2 splits, 1024 threads (16 waves, 4 waves/SIMD).
// S phase : wave (rg = w>>1, bsel = w&1): rows [rg*16,+16), nodes [bsel*16,+16);
//           AqT B-frags in regs (32 VGPR); P = exp2(S), no max-tracking.
// PV phase: wave w owns f-slice [w*16, w*16+16) for ALL 128 rows.
// Stage   : thread t: nodes (t>>7)*4..+3, f = (t&127)*2, +1 (reg 4x2 transpose).
// One barrier per chunk; xsub[2], xT[3], Plds[2] buffering (parities verified).

#define LOADC(c_) { \
  const int c0_ = (c_)*32; \
  _Pragma("unroll") \
  for (int n = 0; n < 4; n++){ \
    int nl_ = c0_ + nq*4 + n; nl_ = nl_ < cnt-1 ? nl_ : cnt-1; \
    rA[n] = *reinterpret_cast<const float2*>(xg + (size_t)nl_*256 + fp*2); } }

// xsub [node][f] pad 264 (b32 writes, uniform banks); xT [f][node] pad 40 + XOR swizzle
#define STAGE(xsP, xtP) { \
  _Pragma("unroll") \
  for (int n = 0; n < 4; n++) \
    *reinterpret_cast<unsigned int*>(&(xsP)[(nq*4 + n)*264 + fp*2]) = cvtpk(rA[n].x, rA[n].y); \
  { const int f0_ = fp*2; \
    uint2 w0_; w0_.x = cvtpk(rA[0].x, rA[1].x); w0_.y = cvtpk(rA[2].x, rA[3].x); \
    *reinterpret_cast<uint2*>(reinterpret_cast<char*>(xtP) + ((f0_*80 + nq*8) ^ (((f0_>>2)&7)<<4))) = w0_; \
    const int f1_ = fp*2 + 1; \
    uint2 w1_; w1_.x = cvtpk(rA[0].y, rA[1].y); w1_.y = cvtpk(rA[2].y, rA[3].y); \
    *reinterpret_cast<uint2*>(reinterpret_cast<char*>(xtP) + ((f1_*80 + nq*8) ^ (((f1_>>2)&7)<<4))) = w1_; } }

__global__ __launch_bounds__(1024, 4) void k_attn(
    const float* __restrict__ x, const int* __restrict__ starts,
    const unsigned short* __restrict__ AqF,
    float* __restrict__ partO, float* __restrict__ partL)
{
  __shared__ __align__(16) unsigned short xsub[2][32*264];
  __shared__ __align__(16) unsigned short xT  [3][256*40];
  __shared__ __align__(16) unsigned short Plds[2][128*40];
  __shared__ __align__(16) float lred[2][128];

  const int tid = threadIdx.x;
  const int wave = tid >> 6, lane = tid & 63, lg = lane >> 4, li = lane & 15;
  const int rg = wave >> 1, bsel = wave & 1;      // S role
  const int fs = wave * 16;                        // PV role
  const int nq = tid >> 7, fp = tid & 127;         // stage role
  const int bid = blockIdx.x;
  const int g = bid >> 1, s = bid & 1;
  const int s0 = starts[g], s1 = starts[g+1];
  const int cntg = s1 - s0;
  const int half = (cntg + 1) >> 1;
  const int nstart = s0 + s*half;
  int cnt = cntg - s*half; cnt = cnt < 0 ? 0 : (cnt > half ? half : cnt);
  const int chunks = (cnt + 31) >> 5;
  const float* xg = x + (size_t)nstart*256;

  // AqT B-fragments for rowgroup rg (loop-invariant, 32 VGPR)
  bf16x8 bfragS[8];
  #pragma unroll
  for (int kb = 0; kb < 8; kb++)
    bfragS[kb] = *reinterpret_cast<const bf16x8*>(AqF + (size_t)(rg*8 + kb)*512 + lane*8);

  f32x4 oacc[8];
  #pragma unroll
  for (int i = 0; i < 8; i++) oacc[i] = f32x4{0.f,0.f,0.f,0.f};
  float rsum = 0.f;

  float2 rA[4];
  if (chunks > 0){
    LOADC(0);
    STAGE(xsub[0], xT[0]);
    if (chunks > 1) LOADC(1);
    block_sync();
  }

  int cur3 = 0;
  for (int c = 0; c < chunks; ++c){
    const int cur2 = c & 1;
    const int nxt3 = (cur3 == 2) ? 0 : cur3 + 1;

    // ---- S(c): rows rg*16..+16, nodes bsel*16..+16 ----
    f32x4 sacc = f32x4{0.f,0.f,0.f,0.f};
    __builtin_amdgcn_s_setprio(1);
    #pragma unroll
    for (int kb = 0; kb < 8; kb++){
      const bf16x8 af = *reinterpret_cast<const bf16x8*>(&xsub[cur2][(bsel*16 + li)*264 + kb*32 + lg*8]);
      sacc = MFMA16(af, bfragS[kb], sacc);
    }
    __builtin_amdgcn_s_setprio(0);

    // ---- P = exp2(S), masked; accumulate row-sum partials ----
    const int nodebase = c*32 + bsel*16 + lg*4;
    float p[4];
    #pragma unroll
    for (int r = 0; r < 4; r++){
      p[r] = (nodebase + r < cnt) ? __builtin_exp2f(sacc[r]) : 0.f;
      rsum += p[r];
    }
    {
      const int row = rg*16 + li;
      uint2 w; w.x = cvtpk(p[0], p[1]); w.y = cvtpk(p[2], p[3]);
      *reinterpret_cast<uint2*>(reinterpret_cast<char*>(Plds[cur2])
          + ((row*80 + bsel*32 + lg*8) ^ (((row>>2)&7)<<4))) = w;
    }

    // ---- stage chunk c+1 (consume rA), refill regs with c+2 ----
    if (c + 1 < chunks){
      STAGE(xsub[cur2 ^ 1], xT[nxt3]);
      if (c + 2 < chunks) LOADC(c + 2);
    }

    block_sync();   // single barrier per chunk

    // ---- PV(c): wave owns f-slice [fs, fs+16) for all 128 rows ----
    const char* xtC = reinterpret_cast<const char*>(xT[cur3]);
    const int fr = fs + li;
    const bf16x8 bv = *reinterpret_cast<const bf16x8*>(xtC + (((fr*80 + lg*16)) ^ (((fr>>2)&7)<<4)));
    const char* plC = reinterpret_cast<const char*>(Plds[cur2]);
    __builtin_amdgcn_s_setprio(1);
    #pragma unroll
    for (int rt = 0; rt < 8; rt++){
      const int prow = rt*16 + li;
      const bf16x8 pa = *reinterpret_cast<const bf16x8*>(plC + (((prow*80 + lg*16)) ^ (((prow>>2)&7)<<4)));
      oacc[rt] = MFMA16(pa, bv, oacc[rt]);
    }
    __builtin_amdgcn_s_setprio(0);
    cur3 = nxt3;
  }

  // ---- row-sum finalize ----
  rsum += __shfl_xor(rsum, 16);
  rsum += __shfl_xor(rsum, 32);
  if (lane < 16) lred[bsel][rg*16 + li] = rsum;
  block_sync();
  const int pbase = bid*128;
  if (tid < 128) partL[pbase + tid] = lred[0][tid] + lred[1][tid];

  #pragma unroll
  for (int rt = 0; rt < 8; rt++){
    #pragma unroll
    for (int r = 0; r < 4; r++){
      partO[(size_t)(pbase + rt*16 + lg*4 + r)*256 + fs + li] = oacc[rt][r];
    }
  }
}

// ---------------- combine partials + out-proj GEMM ----------------
__global__ __launch_bounds__(512, 1) void k_out(
    const float* __restrict__ partO, const float* __restrict__ partL,
    const unsigned short* __restrict__ Cmat, const float* __restrict__ cvec,
    float* __restrict__ out)
{
  __shared__ __align__(16) unsigned short plds[16*1024];
  __shared__ float sinv[64];
  const int tid = threadIdx.x;
  const int g = blockIdx.x >> 1, qh = blockIdx.x & 1;
  const int p0 = 2*g, p1 = 2*g + 1;
  if (tid < 64){
    const int h = tid >> 4, qr = tid & 15;
    const int row = h*32 + qh*16 + qr;
    const float L = partL[p0*128 + row] + partL[p1*128 + row];
    sinv[tid] = 1.f / L;
  }
  __syncthreads();
  #pragma unroll
  for (int i = 0; i < 8; i++){
    const int idx = tid + i*512;
    const int qr = idx >> 8;            // 0..15
    const int cg = idx & 255;           // group of 4 cols
    const int h = cg >> 6, f4 = (cg & 63)*4;
    const int row = h*32 + qh*16 + qr;
    const float4 o0 = *reinterpret_cast<const float4*>(&partO[(size_t)(p0*128 + row)*256 + f4]);
    const float4 o1 = *reinterpret_cast<const float4*>(&partO[(size_t)(p1*128 + row)*256 + f4]);
    const float sc = sinv[h*16 + qr];
    uint2 w; w.x = cvtpk((o0.x+o1.x)*sc, (o0.y+o1.y)*sc);
             w.y = cvtpk((o0.z+o1.z)*sc, (o0.w+o1.w)*sc);
    const int col4 = cg*4;
    const int bc = (col4*2) ^ ((qr & 7) << 4);
    *reinterpret_cast<uint2*>(reinterpret_cast<char*>(plds) + qr*2048 + bc) = w;
  }
  __syncthreads();
  const int wave = tid >> 6, lane = tid & 63, lg = lane >> 4, li = lane & 15;
  f32x4 acc0 = {0.f,0.f,0.f,0.f}, acc1 = {0.f,0.f,0.f,0.f};
  const float cv0 = cvec[wave*32 + li], cv1 = cvec[wave*32 + 16 + li];
  const unsigned short* cb0 = Cmat + (size_t)(wave*32 + li)*1024;
  const unsigned short* cb1 = Cmat + (size_t)(wave*32 + 16 + li)*1024;
  #pragma unroll 8
  for (int kb = 0; kb < 32; kb++){
    const int bc = ((kb*32 + lg*8)*2) ^ ((li & 7) << 4);
    const bf16x8 aa = *reinterpret_cast<const bf16x8*>(reinterpret_cast<const char*>(plds) + li*2048 + bc);
    const bf16x8 b0 = *reinterpret_cast<const bf16x8*>(cb0 + kb*32 + lg*8);
    const bf16x8 b1 = *reinterpret_cast<const bf16x8*>(cb1 + kb*32 + lg*8);
    acc0 = MFMA16(aa, b0, acc0);
    acc1 = MFMA16(aa, b1, acc1);
  }
  #pragma unroll
  for (int r = 0; r < 4; r++){
    const int q = lg*4 + r;
    const size_t orow = (size_t)(g*32 + qh*16 + q)*256;
    out[orow + wave*32 + li]      = acc0[r] + cv0;
    out[orow + wave*32 + 16 + li] = acc1[r] + cv1;
  }
}

// ---------------- launch ----------------

extern "C" void kernel_launch(void* const* d_in, const int* in_sizes, int n_in,
                              void* d_out, int out_size, void* d_ws, size_t ws_size,
                              hipStream_t stream)
{
  const float* x       = (const float*)d_in[0];
  const int*   batch   = (const int*)d_in[1];
  const float* queries = (const float*)d_in[2];
  const float* ipw     = (const float*)d_in[3];
  const float* ipb     = (const float*)d_in[4];
  const float* opw     = (const float*)d_in[5];
  const float* opb     = (const float*)d_in[6];
  float* out = (float*)d_out;
  const int total = in_sizes[1];

  char* w = (char*)d_ws;
  int*            starts = (int*)(w);
  unsigned short* AqF    = (unsigned short*)(w + 36*1024);
  unsigned short* Cmat   = (unsigned short*)(w + 102*1024);
  float*          cvec   = (float*)(w + 616*1024);
  float*          partO  = (float*)(w + (size_t)1024*1024);
  float*          partL  = (float*)(w + (size_t)1024*1024 + (size_t)256*128*256*4);

  k_prep<<<544, 256, 0, stream>>>(queries, ipw, ipb, opw, opb, batch, total,
                                  starts, AqF, Cmat, cvec);
  k_attn<<<256, 1024, 0, stream>>>(x, starts, AqF, partO, partL);
  k_out<<<256, 512, 0, stream>>>(partO, partL, Cmat, cvec, out);
}

// Round 7
// 104.996 us; speedup vs baseline: 1.0895x; 1.0895x over previous
//
#include <hip/hip_runtime.h>
#include <hip/hip_bf16.h>

typedef __bf16 bf16x8 __attribute__((ext_vector_type(8)));
typedef float  f32x4  __attribute__((ext_vector_type(4)));

#define MFMA16(a,b,c) __builtin_amdgcn_mfma_f32_16x16x32_bf16((a),(b),(c),0,0,0)

__device__ __forceinline__ unsigned short f2bf(float f){
  unsigned int u = __float_as_uint(f);
  u += 0x7fffu + ((u >> 16) & 1u);
  return (unsigned short)(u >> 16);
}

// pack 2 f32 -> 2 bf16 in one instr (RTE)
__device__ __forceinline__ unsigned int cvtpk(float lo, float hi){
  unsigned int r;
  asm("v_cvt_pk_bf16_f32 %0, %1, %2" : "=v"(r) : "v"(lo), "v"(hi));
  return r;
}

// LDS-visibility sync WITHOUT vmcnt(0) drain (keeps global loads in flight)
__device__ __forceinline__ void block_sync(){
  asm volatile("s_waitcnt lgkmcnt(0)" ::: "memory");
  __builtin_amdgcn_s_barrier();
}

constexpr float SCALE_LOG2E = 0.125f * 1.4426950408889634f; // 1/sqrt(64) * log2(e)

// ---------------- merged prep kernel ----------------
// blocks 0..31: qs + AqT fragments ; 32..287: Cmat+cvec ; 288..543: starts scan
__global__ void k_prep(const float* __restrict__ queries, const float* __restrict__ ipw,
                       const float* __restrict__ ipb, const float* __restrict__ opw,
                       const float* __restrict__ opb, const int* __restrict__ batch,
                       int total, int* __restrict__ starts,
                       unsigned short* __restrict__ AqF,
                       unsigned short* __restrict__ Cmat, float* __restrict__ cvec)
{
  __shared__ __align__(16) float sh[256];
  __shared__ __align__(16) float sh2[256];
  const int t = threadIdx.x, bid = blockIdx.x;

  if (bid < 32){
    const int q = bid;
    sh[t] = queries[q*256 + t];
    __syncthreads();
    const float* wr = ipw + (size_t)t*256;
    float acc = 0.f;
    #pragma unroll 8
    for (int j = 0; j < 256; j += 4){
      float4 wv = *reinterpret_cast<const float4*>(wr + j);
      float4 qv = *reinterpret_cast<const float4*>(&sh[j]);
      acc += wv.x*qv.x + wv.y*qv.y + wv.z*qv.z + wv.w*qv.w;
    }
    sh2[t] = acc + ipb[t];
    __syncthreads();
    #pragma unroll
    for (int h = 0; h < 4; h++){
      const float* wk = ipw + (size_t)(256 + h*64)*256 + t;
      float a2 = 0.f;
      #pragma unroll 8
      for (int d = 0; d < 64; d++) a2 += sh2[h*64 + d] * wk[(size_t)d*256];
      // B-frag layout: AqF[rg=h*2+qh][kb=f>>5][lane=((f>>3)&3)*16 + (q&15)][j=f&7]
      const int dst = ((h*2 + (q>>4))*8 + (t>>5))*512 + (((t>>3)&3)*16 + (q&15))*8 + (t&7);
      AqF[dst] = f2bf(a2 * SCALE_LOG2E);
    }
  } else if (bid < 288){
    const int g = bid - 32;
    sh[t] = opw[(size_t)g*256 + t];
    __syncthreads();
    #pragma unroll
    for (int h = 0; h < 4; h++){
      const float* wv = ipw + (size_t)(512 + h*64)*256 + t;
      float acc = 0.f;
      #pragma unroll 8
      for (int d = 0; d < 64; d++) acc += wv[(size_t)d*256] * sh[h*64 + d];
      Cmat[(size_t)g*1024 + h*256 + t] = f2bf(acc);
    }
    sh2[t] = ipb[512 + t] * sh[t];
    __syncthreads();
    for (int off = 128; off > 0; off >>= 1){
      if (t < off) sh2[t] += sh2[t + off];
      __syncthreads();
    }
    if (t == 0) cvec[g] = sh2[0] + opb[g];
  } else {
    const int sb = bid - 288;
    const int i0 = sb*1024 + t*4;
    if (i0 + 3 < total){
      if (i0 == 0) starts[0] = 0;
      const int4 b4 = *reinterpret_cast<const int4*>(batch + i0);
      if (b4.y != b4.x) starts[b4.y] = i0 + 1;
      if (b4.z != b4.y) starts[b4.z] = i0 + 2;
      if (b4.w != b4.z) starts[b4.w] = i0 + 3;
      if (i0 + 4 < total){
        const int nxt = batch[i0 + 4];
        if (nxt != b4.w) starts[nxt] = i0 + 4;
      } else {
        starts[128] = total;
      }
    }
  }
}

// ---------------- fused attention over raw x (no-max softmax) ----------------
// grid 256 = graph*2 splits, 1024 threads (16 waves, 4 waves/SIMD).
// WAVE SPECIALIZATION:
//  S-waves 0..7  (rg2 = w>>1, bsel = w&1): rows [rg2*32,+32) x nodes [bsel*16,+16);
//        AqT B-frags in regs (64 VGPR); A-frag read once feeds 2 MFMAs.
//  PV-waves 8..15 (pw = w-8): f-slice [pw*32,+32) for ALL 128 rows; pa feeds 2 MFMAs.
// Both loops: stage(c+1) pre-barrier(c); S computes pre-barrier, PV post-barrier.
// Buffers: xsub[2], xT[3], Plds[2] (race matrix verified).
// Stage role (all 1024 threads): nodes (t>>7)*4..+3, f = (t&127)*2,+1.

#define LOADC(c_) { \
  const int c0_ = (c_)*32; \
  _Pragma("unroll") \
  for (int n = 0; n < 4; n++){ \
    int nl_ = c0_ + nq*4 + n; nl_ = nl_ < cnt-1 ? nl_ : cnt-1; \
    rA[n] = *reinterpret_cast<const float2*>(xg + (size_t)nl_*256 + fp*2); } }

// xsub [node][f] pad 264 ; xT [f][node] pad 40 + XOR swizzle
#define STAGE(xsP, xtP) { \
  _Pragma("unroll") \
  for (int n = 0; n < 4; n++) \
    *reinterpret_cast<unsigned int*>(&(xsP)[(nq*4 + n)*264 + fp*2]) = cvtpk(rA[n].x, rA[n].y); \
  { const int f0_ = fp*2; \
    uint2 w0_; w0_.x = cvtpk(rA[0].x, rA[1].x); w0_.y = cvtpk(rA[2].x, rA[3].x); \
    *reinterpret_cast<uint2*>(reinterpret_cast<char*>(xtP) + ((f0_*80 + nq*8) ^ (((f0_>>2)&7)<<4))) = w0_; \
    const int f1_ = fp*2 + 1; \
    uint2 w1_; w1_.x = cvtpk(rA[0].y, rA[1].y); w1_.y = cvtpk(rA[2].y, rA[3].y); \
    *reinterpret_cast<uint2*>(reinterpret_cast<char*>(xtP) + ((f1_*80 + nq*8) ^ (((f1_>>2)&7)<<4))) = w1_; } }

__global__ __launch_bounds__(1024, 4) void k_attn(
    const float* __restrict__ x, const int* __restrict__ starts,
    const unsigned short* __restrict__ AqF,
    float* __restrict__ partO, float* __restrict__ partL)
{
  __shared__ __align__(16) unsigned short xsub[2][32*264];
  __shared__ __align__(16) unsigned short xT  [3][256*40];
  __shared__ __align__(16) unsigned short Plds[2][128*40];
  __shared__ __align__(16) float lred[2][128];

  const int tid = threadIdx.x;
  const int wave = tid >> 6, lane = tid & 63, lg = lane >> 4, li = lane & 15;
  const int nq = tid >> 7, fp = tid & 127;         // stage role
  const int bid = blockIdx.x;
  const int g = bid >> 1, s = bid & 1;
  const int s0 = starts[g], s1 = starts[g+1];
  const int cntg = s1 - s0;
  const int half = (cntg + 1) >> 1;
  const int nstart = s0 + s*half;
  int cnt = cntg - s*half; cnt = cnt < 0 ? 0 : (cnt > half ? half : cnt);
  const int chunks = (cnt + 31) >> 5;
  const float* xg = x + (size_t)nstart*256;
  const int pbase = bid*128;

  float2 rA[4];
  if (chunks > 0){
    LOADC(0);
    STAGE(xsub[0], xT[0]);
    if (chunks > 1) LOADC(1);
    block_sync();
  }

  if (wave < 8){
    // ================= S-waves =================
    const int rg2 = wave >> 1, bsel = wave & 1;
    bf16x8 bfragS[2][8];
    #pragma unroll
    for (int rf = 0; rf < 2; rf++)
      #pragma unroll
      for (int kb = 0; kb < 8; kb++)
        bfragS[rf][kb] = *reinterpret_cast<const bf16x8*>(AqF + (size_t)((rg2*2 + rf)*8 + kb)*512 + lane*8);

    float rsum0 = 0.f, rsum1 = 0.f;
    const int row0 = rg2*32 + li, row1 = rg2*32 + 16 + li;
    const int pbyte0 = (row0*80 + bsel*32 + lg*8) ^ (((row0>>2)&7)<<4);
    const int pbyte1 = (row1*80 + bsel*32 + lg*8) ^ (((row1>>2)&7)<<4);

    int cur3 = 0;
    for (int c = 0; c < chunks; ++c){
      const int cur2 = c & 1;
      const int nxt3 = (cur3 == 2) ? 0 : cur3 + 1;

      f32x4 sc0 = f32x4{0.f,0.f,0.f,0.f}, sc1 = f32x4{0.f,0.f,0.f,0.f};
      __builtin_amdgcn_s_setprio(1);
      #pragma unroll
      for (int kb = 0; kb < 8; kb++){
        const bf16x8 af = *reinterpret_cast<const bf16x8*>(&xsub[cur2][(bsel*16 + li)*264 + kb*32 + lg*8]);
        sc0 = MFMA16(af, bfragS[0][kb], sc0);
        sc1 = MFMA16(af, bfragS[1][kb], sc1);
      }
      __builtin_amdgcn_s_setprio(0);

      const int nodebase = c*32 + bsel*16 + lg*4;
      float p0[4], p1[4];
      #pragma unroll
      for (int r = 0; r < 4; r++){
        const bool v = (nodebase + r) < cnt;
        p0[r] = v ? __builtin_exp2f(sc0[r]) : 0.f;
        p1[r] = v ? __builtin_exp2f(sc1[r]) : 0.f;
        rsum0 += p0[r]; rsum1 += p1[r];
      }
      {
        char* pl = reinterpret_cast<char*>(Plds[cur2]);
        uint2 w0; w0.x = cvtpk(p0[0], p0[1]); w0.y = cvtpk(p0[2], p0[3]);
        uint2 w1; w1.x = cvtpk(p1[0], p1[1]); w1.y = cvtpk(p1[2], p1[3]);
        *reinterpret_cast<uint2*>(pl + pbyte0) = w0;
        *reinterpret_cast<uint2*>(pl + pbyte1) = w1;
      }

      if (c + 1 < chunks){
        STAGE(xsub[cur2 ^ 1], xT[nxt3]);
        if (c + 2 < chunks) LOADC(c + 2);
      }
      block_sync();
      cur3 = nxt3;
    }

    rsum0 += __shfl_xor(rsum0, 16); rsum0 += __shfl_xor(rsum0, 32);
    rsum1 += __shfl_xor(rsum1, 16); rsum1 += __shfl_xor(rsum1, 32);
    if (lane < 16){
      lred[bsel][rg2*32 + li]      = rsum0;
      lred[bsel][rg2*32 + 16 + li] = rsum1;
    }
  } else {
    // ================= PV-waves =================
    const int pw = wave - 8, fs = pw*32;
    f32x4 oacc[8][2];
    #pragma unroll
    for (int i = 0; i < 8; i++){ oacc[i][0] = f32x4{0.f,0.f,0.f,0.f}; oacc[i][1] = f32x4{0.f,0.f,0.f,0.f}; }
    const int fr0 = fs + li, fr1 = fs + 16 + li;
    const int bvb0 = (fr0*80 + lg*16) ^ (((fr0>>2)&7)<<4);
    const int bvb1 = (fr1*80 + lg*16) ^ (((fr1>>2)&7)<<4);

    int cur3 = 0;
    for (int c = 0; c < chunks; ++c){
      const int cur2 = c & 1;
      const int nxt3 = (cur3 == 2) ? 0 : cur3 + 1;

      if (c + 1 < chunks){
        STAGE(xsub[cur2 ^ 1], xT[nxt3]);
        if (c + 2 < chunks) LOADC(c + 2);
      }
      block_sync();

      const char* xtC = reinterpret_cast<const char*>(xT[cur3]);
      const bf16x8 bv0 = *reinterpret_cast<const bf16x8*>(xtC + bvb0);
      const bf16x8 bv1 = *reinterpret_cast<const bf16x8*>(xtC + bvb1);
      const char* plC = reinterpret_cast<const char*>(Plds[cur2]);
      __builtin_amdgcn_s_setprio(1);
      #pragma unroll
      for (int rt = 0; rt < 8; rt++){
        const int prow = rt*16 + li;
        const bf16x8 pa = *reinterpret_cast<const bf16x8*>(plC + ((prow*80 + lg*16) ^ (((prow>>2)&7)<<4)));
        oacc[rt][0] = MFMA16(pa, bv0, oacc[rt][0]);
        oacc[rt][1] = MFMA16(pa, bv1, oacc[rt][1]);
      }
      __builtin_amdgcn_s_setprio(0);
      cur3 = nxt3;
    }

    #pragma unroll
    for (int rt = 0; rt < 8; rt++){
      #pragma unroll
      for (int r = 0; r < 4; r++){
        const size_t orow = (size_t)(pbase + rt*16 + lg*4 + r)*256;
        partO[orow + fs + li]      = oacc[rt][0][r];
        partO[orow + fs + 16 + li] = oacc[rt][1][r];
      }
    }
  }

  block_sync();
  if (tid < 128) partL[pbase + tid] = lred[0][tid] + lred[1][tid];
}

// ---------------- combine partials + out-proj GEMM ----------------
__global__ __launch_bounds__(512, 1) void k_out(
    const float* __restrict__ partO, const float* __restrict__ partL,
    const unsigned short* __restrict__ Cmat, const float* __restrict__ cvec,
    float* __restrict__ out)
{
  __shared__ __align__(16) unsigned short plds[16*1024];
  __shared__ float sinv[64];
  const int tid = threadIdx.x;
  const int g = blockIdx.x >> 1, qh = blockIdx.x & 1;
  const int p0 = 2*g, p1 = 2*g + 1;
  if (tid < 64){
    const int h = tid >> 4, qr = tid & 15;
    const int row = h*32 + qh*16 + qr;
    const float L = partL[p0*128 + row] + partL[p1*128 + row];
    sinv[tid] = 1.f / L;
  }
  __syncthreads();
  #pragma unroll
  for (int i = 0; i < 8; i++){
    const int idx = tid + i*512;
    const int qr = idx >> 8;            // 0..15
    const int cg = idx & 255;           // group of 4 cols
    const int h = cg >> 6, f4 = (cg & 63)*4;
    const int row = h*32 + qh*16 + qr;
    const float4 o0 = *reinterpret_cast<const float4*>(&partO[(size_t)(p0*128 + row)*256 + f4]);
    const float4 o1 = *reinterpret_cast<const float4*>(&partO[(size_t)(p1*128 + row)*256 + f4]);
    const float sc = sinv[h*16 + qr];
    uint2 w; w.x = cvtpk((o0.x+o1.x)*sc, (o0.y+o1.y)*sc);
             w.y = cvtpk((o0.z+o1.z)*sc, (o0.w+o1.w)*sc);
    const int col4 = cg*4;
    const int bc = (col4*2) ^ ((qr & 7) << 4);
    *reinterpret_cast<uint2*>(reinterpret_cast<char*>(plds) + qr*2048 + bc) = w;
  }
  __syncthreads();
  const int wave = tid >> 6, lane = tid & 63, lg = lane >> 4, li = lane & 15;
  f32x4 acc0 = {0.f,0.f,0.f,0.f}, acc1 = {0.f,0.f,0.f,0.f};
  const float cv0 = cvec[wave*32 + li], cv1 = cvec[wave*32 + 16 + li];
  const unsigned short* cb0 = Cmat + (size_t)(wave*32 + li)*1024;
  const unsigned short* cb1 = Cmat + (size_t)(wave*32 + 16 + li)*1024;
  #pragma unroll 8
  for (int kb = 0; kb < 32; kb++){
    const int bc = ((kb*32 + lg*8)*2) ^ ((li & 7) << 4);
    const bf16x8 aa = *reinterpret_cast<const bf16x8*>(reinterpret_cast<const char*>(plds) + li*2048 + bc);
    const bf16x8 b0 = *reinterpret_cast<const bf16x8*>(cb0 + kb*32 + lg*8);
    const bf16x8 b1 = *reinterpret_cast<const bf16x8*>(cb1 + kb*32 + lg*8);
    acc0 = MFMA16(aa, b0, acc0);
    acc1 = MFMA16(aa, b1, acc1);
  }
  #pragma unroll
  for (int r = 0; r < 4; r++){
    const int q = lg*4 + r;
    const size_t orow = (size_t)(g*32 + qh*16 + q)*256;
    out[orow + wave*32 + li]      = acc0[r] + cv0;
    out[orow + wave*32 + 16 + li] = acc1[r] + cv1;
  }
}

// ---------------- launch ----------------

extern "C" void kernel_launch(void* const* d_in, const int* in_sizes, int n_in,
                              void* d_out, int out_size, void* d_ws, size_t ws_size,
                              hipStream_t stream)
{
  const float* x       = (const float*)d_in[0];
  const int*   batch   = (const int*)d_in[1];
  const float* queries = (const float*)d_in[2];
  const float* ipw     = (const float*)d_in[3];
  const float* ipb     = (const float*)d_in[4];
  const float* opw     = (const float*)d_in[5];
  const float* opb     = (const float*)d_in[6];
  float* out = (float*)d_out;
  const int total = in_sizes[1];

  char* w = (char*)d_ws;
  int*            starts = (int*)(w);
  unsigned short* AqF    = (unsigned short*)(w + 36*1024);
  unsigned short* Cmat   = (unsigned short*)(w + 102*1024);
  float*          cvec   = (float*)(w + 616*1024);
  float*          partO  = (float*)(w + (size_t)1024*1024);
  float*          partL  = (float*)(w + (size_t)1024*1024 + (size_t)256*128*256*4);

  k_prep<<<544, 256, 0, stream>>>(queries, ipw, ipb, opw, opb, batch, total,
                                  starts, AqF, Cmat, cvec);
  k_attn<<<256, 1024, 0, stream>>>(x, starts, AqF, partO, partL);
  k_out<<<256, 512, 0, stream>>>(partO, partL, Cmat, cvec, out);
}